// Round 3
// baseline (79.870 us; speedup 1.0000x reference)
//
#include <hip/hip_runtime.h>
#include <math.h>

#define NATOMS 2000
#define KNBR   24
#define BLOCK  256
#define NWAVE  4        // BLOCK / 64
#define WHCAP  48       // per-wave d<=5.1 hit cap   (lambda ~14, P(overflow) ~ 1e-8)
#define WACAP  24       // per-wave d<=3.5 cand cap  (lambda ~4.5, P(overflow) ~ 1e-10)
#define NFEAT  1904.0f  // 7*16 + 28*64

__device__ __forceinline__ float wave_reduce_add(float v) {
    #pragma unroll
    for (int off = 32; off > 0; off >>= 1) v += __shfl_down(v, off, 64);
    return v;
}

// rank of this lane among set bits below it in a 64-bit wave mask (v_mbcnt pair)
__device__ __forceinline__ int mask_rank_below(unsigned long long m) {
    return (int)__builtin_amdgcn_mbcnt_hi((unsigned)(m >> 32),
                 __builtin_amdgcn_mbcnt_lo((unsigned)m, 0u));
}

// One block per atom i; each of the 4 waves scans an interleaved quarter of the
// atoms and compacts hits into a PRIVATE LDS segment using register-based ballot
// compaction (no LDS atomics, no shuffles -- the ballot mask is wave-uniform so
// every lane tracks the running base in a register).
__global__ __launch_bounds__(BLOCK) void aev_block_kernel(
        const float* __restrict__ pos, float* __restrict__ partial) {
    constexpr float RCR = 5.1f, RCA = 3.5f;
    constexpr float ETA_R = 19.7f, ZETA = 14.1f, ETA_A = 12.5f;
    constexpr float PI = 3.14159265358979323846f;

    __shared__ float hd2[NWAVE][WHCAP];
    __shared__ int   hj [NWAVE][WHCAP];
    __shared__ float ad [NWAVE][WACAP];
    __shared__ int   aj [NWAVE][WACAP];
    __shared__ int   acnt[NWAVE];
    __shared__ float nbx[KNBR], nby[KNBR], nbz[KNBR], nbd[KNBR], nbfc[KNBR];
    __shared__ float red[NWAVE];

    const int tid  = threadIdx.x;
    const int w    = tid >> 6;
    const int lane = tid & 63;
    const int i    = blockIdx.x;

    // wave-uniform scalar loads of atom i's position
    const float xi = pos[3 * i + 0], yi = pos[3 * i + 1], zi = pos[3 * i + 2];

    // --- Phase 1a: scan; per-wave private ballot compaction (atomic-free) ---
    int hbase = 0;
    #pragma unroll 4
    for (int it = 0; it < 8; it++) {
        int j  = w * 64 + it * 256 + lane;         // max 2047 -> mask
        int jc = j < NATOMS ? j : 0;
        float dx = pos[3 * jc + 0] - xi;
        float dy = pos[3 * jc + 1] - yi;
        float dz = pos[3 * jc + 2] - zi;
        float d2 = dx * dx + dy * dy + dz * dz;
        bool hit = (j < NATOMS) && (j != i) && (d2 <= RCR * RCR);
        unsigned long long m = __ballot(hit);
        if (hit) {
            int idx = hbase + mask_rank_below(m);
            if (idx < WHCAP) { hd2[w][idx] = d2; hj[w][idx] = j; }
        }
        hbase += __popcll(m);   // wave-uniform update, stays in registers
    }

    // --- Phase 1b: dense radial body on this wave's hits; angular sub-compact ---
    int hcnt = min(hbase, WHCAP);
    float rsum = 0.0f;
    float d = 0.0f, d2v = 1e9f;
    bool act = lane < hcnt;
    {
        int cl = min(lane, WHCAP - 1);
        if (act) d2v = hd2[w][cl];
        if (act) {
            d = sqrtf(d2v);
            float fc = 0.5f * __cosf(d * (PI / RCR)) + 0.5f;
            float s = 0.0f;
            #pragma unroll
            for (int r = 0; r < 16; r++) {
                float t = d - (0.8f + 0.26875f * (float)r);
                s += __expf(-ETA_R * t * t);
            }
            rsum = 0.25f * fc * s;
        }
        bool ahit = act && (d2v <= RCA * RCA);
        unsigned long long m = __ballot(ahit);
        if (ahit) {
            int idx = mask_rank_below(m);
            if (idx < WACAP) { ad[w][idx] = d; aj[w][idx] = hj[w][min(lane, WHCAP - 1)]; }
        }
        if (lane == 0) acnt[w] = min((int)__popcll(m), WACAP);
    }
    __syncthreads();

    // --- Phase 2: merge 4 segments, rank-select min(cnt,24) nearest ---
    int c0 = acnt[0], c1 = acnt[1], c2 = acnt[2], c3 = acnt[3];
    int cnt = min(c0 + c1 + c2 + c3, 64);
    int M   = min(cnt, KNBR);
    if (tid < cnt) {
        int t = tid, seg = 0;
        if (t >= c0) { t -= c0; seg = 1;
            if (t >= c1) { t -= c1; seg = 2;
                if (t >= c2) { t -= c2; seg = 3; } } }
        float dt = ad[seg][t];
        int   jt = aj[seg][t];
        int rank = 0;
        for (int s = 0; s < NWAVE; s++) {
            int cs = acnt[s];
            for (int u = 0; u < cs; u++) {
                float du = ad[s][u];
                if (du < dt || (du == dt && aj[s][u] < jt)) rank++;
            }
        }
        if (rank < KNBR) {
            nbx[rank]  = pos[3 * jt + 0] - xi;
            nby[rank]  = pos[3 * jt + 1] - yi;
            nbz[rank]  = pos[3 * jt + 2] - zi;
            nbd[rank]  = dt;
            nbfc[rank] = 0.5f * __cosf(dt * (PI / RCA)) + 0.5f;
        }
    }
    __syncthreads();

    // --- Phase 3: angular over unordered pairs; cos(theta-s) via addition formula
    //     (exact identity: cos(t)=ca known, sin(t)=sqrt(1-ca^2) since t in [0,pi];
    //      z and z+4 shifts differ by pi -> fold into (0.5+g)^z + (0.5-g)^z) ---
    const float CZ[4] = { 0.92387953251f, 0.38268343236f, -0.38268343236f, -0.92387953251f };
    const float SZ[4] = { 0.38268343236f, 0.92387953251f,  0.92387953251f,  0.38268343236f };
    float asum = 0.0f;
    int npairs = M * (M - 1) / 2;
    for (int p = tid; p < npairs; p += BLOCK) {
        int a = 0, rem = p;
        while (rem >= M - 1 - a) { rem -= M - 1 - a; a++; }
        int b = a + 1 + rem;

        float ra = nbd[a], rb = nbd[b];
        float dot = nbx[a] * nbx[b] + nby[a] * nby[b] + nbz[a] * nbz[b];
        float ca = 0.95f * dot / (ra * rb);
        float sa = sqrtf(fmaxf(0.0f, 1.0f - ca * ca));

        float f1 = 0.0f;
        #pragma unroll
        for (int z = 0; z < 4; z++) {
            float g = 0.5f * (ca * CZ[z] + sa * SZ[z]);
            f1 += __powf(fmaxf(0.5f + g, 1e-20f), ZETA);
            f1 += __powf(fmaxf(0.5f - g, 1e-20f), ZETA);
        }
        float avg = 0.5f * (ra + rb);
        float f2  = 0.0f;
        #pragma unroll
        for (int s8 = 0; s8 < 8; s8++) {
            float t = avg - (0.8f + 0.3375f * (float)s8);
            f2 += __expf(-ETA_A * t * t);
        }
        asum += 2.0f * nbfc[a] * nbfc[b] * f1 * f2;
    }

    // --- Block reduction; plain per-atom store ---
    float psum = wave_reduce_add(rsum + asum);
    if (lane == 0) red[w] = psum;
    __syncthreads();
    if (tid == 0) {
        float total = 0.0f;
        #pragma unroll
        for (int q = 0; q < NWAVE; q++) total += red[q];
        partial[i] = total;
    }
}

__global__ __launch_bounds__(BLOCK) void finalize_kernel(
        const float* __restrict__ partial, float* __restrict__ out) {
    __shared__ float red[BLOCK / 64];
    const int tid = threadIdx.x;
    float v = 0.0f;
    for (int c = tid; c < NATOMS; c += BLOCK) v += partial[c];
    v = wave_reduce_add(v);
    if ((tid & 63) == 0) red[tid >> 6] = v;
    __syncthreads();
    if (tid == 0) {
        float total = 0.0f;
        #pragma unroll
        for (int q = 0; q < BLOCK / 64; q++) total += red[q];
        out[0] = total / ((float)NATOMS * NFEAT);
    }
}

extern "C" void kernel_launch(void* const* d_in, const int* in_sizes, int n_in,
                              void* d_out, int out_size, void* d_ws, size_t ws_size,
                              hipStream_t stream) {
    // d_in[0]: species (int32) -- provably irrelevant: the one-hot/scatter bins
    // partition the sum and the final mean sums over all bins.
    // d_in[1]: positions (float32, N x 3).
    const float* pos = (const float*)d_in[1];
    float* partial = (float*)d_ws;   // NATOMS floats, plain stores, no init needed

    aev_block_kernel<<<NATOMS, BLOCK, 0, stream>>>(pos, partial);
    finalize_kernel<<<1, BLOCK, 0, stream>>>(partial, (float*)d_out);
}